// Round 1
// baseline (304.313 us; speedup 1.0000x reference)
//
#include <hip/hip_runtime.h>
#include <hip/hip_bf16.h>
#include <math.h>

// Problem constants (from reference setup_inputs)
#define BB 2
#define CC 32
#define HH 128
#define WW 160
#define DD 32
#define NN 4
#define HW (HH * WW)        // 20480
#define GG 8

// ---------------------------------------------------------------------------
// Kernel 1: per-(b,src) projection matrices.
// ref_new = [Kref3x3 @ Eref[:3,:4] ; Eref[3,:]]  (same for src)
// P = src_new @ inv(ref_new); store rot (9) + trans (3) per (b,n).
// FP64 Gauss-Jordan with partial pivoting (8 threads total; cost negligible).
// ---------------------------------------------------------------------------
__global__ void mat_kernel(const float* __restrict__ proj, float* __restrict__ mats) {
    int t = threadIdx.x;
    if (t >= BB * NN) return;
    int b = t >> 2, n = t & 3;
    const float* Er = proj + ((size_t)(b * (NN + 1) + 0) * 2 + 0) * 16;
    const float* Kr = proj + ((size_t)(b * (NN + 1) + 0) * 2 + 1) * 16;
    const float* Es = proj + ((size_t)(b * (NN + 1) + n + 1) * 2 + 0) * 16;
    const float* Ks = proj + ((size_t)(b * (NN + 1) + n + 1) * 2 + 1) * 16;

    double A[4][4], Bm[4][4];
    for (int r = 0; r < 4; r++)
        for (int c = 0; c < 4; c++) {
            if (r < 3) {
                A[r][c]  = (double)Kr[r*4+0]*Er[0*4+c] + (double)Kr[r*4+1]*Er[1*4+c] + (double)Kr[r*4+2]*Er[2*4+c];
                Bm[r][c] = (double)Ks[r*4+0]*Es[0*4+c] + (double)Ks[r*4+1]*Es[1*4+c] + (double)Ks[r*4+2]*Es[2*4+c];
            } else {
                A[r][c]  = (double)Er[12 + c];
                Bm[r][c] = (double)Es[12 + c];
            }
        }
    // Gauss-Jordan inverse of A -> M[:,4:8]
    double M[4][8];
    for (int i = 0; i < 4; i++)
        for (int j = 0; j < 4; j++) { M[i][j] = A[i][j]; M[i][4+j] = (i == j) ? 1.0 : 0.0; }
    for (int col = 0; col < 4; col++) {
        int piv = col;
        for (int r = col + 1; r < 4; r++)
            if (fabs(M[r][col]) > fabs(M[piv][col])) piv = r;
        if (piv != col)
            for (int j = 0; j < 8; j++) { double tmp = M[col][j]; M[col][j] = M[piv][j]; M[piv][j] = tmp; }
        double pv = M[col][col];
        for (int j = 0; j < 8; j++) M[col][j] /= pv;
        for (int r = 0; r < 4; r++) {
            if (r == col) continue;
            double f = M[r][col];
            for (int j = 0; j < 8; j++) M[r][j] -= f * M[col][j];
        }
    }
    float* o = mats + t * 12;
    for (int i = 0; i < 3; i++) {
        double p0 = 0, p1 = 0, p2 = 0, p3 = 0;
        for (int k = 0; k < 4; k++) {
            p0 += Bm[i][k] * M[k][4+0];
            p1 += Bm[i][k] * M[k][4+1];
            p2 += Bm[i][k] * M[k][4+2];
            p3 += Bm[i][k] * M[k][4+3];
        }
        o[i*3+0] = (float)p0; o[i*3+1] = (float)p1; o[i*3+2] = (float)p2;
        o[9 + i] = (float)p3;
    }
}

// ---------------------------------------------------------------------------
// Kernel 2: generic [32][HW] -> [HW][32] transpose per slab (LDS tile).
// Used for src (8 slabs), ref (2 slabs), depth (2 slabs) — all are 32 x 20480.
// ---------------------------------------------------------------------------
__global__ __launch_bounds__(256) void transpose32(const float* __restrict__ in,
                                                   float* __restrict__ out) {
    __shared__ float t[32][33];
    int slab = blockIdx.y;
    int hw0 = blockIdx.x * 32;
    int tx = threadIdx.x & 31, ty = threadIdx.x >> 5;
    const float* ip = in + (size_t)slab * 32 * HW + hw0;
#pragma unroll
    for (int i = 0; i < 4; i++) {
        int c = ty + i * 8;
        t[c][tx] = ip[(size_t)c * HW + tx];
    }
    __syncthreads();
    float* op = out + (size_t)slab * 32 * HW + (size_t)hw0 * 32;
#pragma unroll
    for (int i = 0; i < 4; i++) {
        int hl = ty + i * 8;
        op[hl * 32 + tx] = t[tx][hl];
    }
}

// ---------------------------------------------------------------------------
// Kernel 3: fused main kernel.
// One 32-lane segment per ref pixel, lane = depth index d.
// Per source: homography -> bilinear gather (channels-last, dwordx4 per group)
// -> group dots -> softmax over D (shuffle) -> weighted accumulation.
// Final: reg_w projection -> softmax over D -> attn_weight + argmax depth.
// ---------------------------------------------------------------------------
__global__ __launch_bounds__(256) void main_kernel(
    const float* __restrict__ srcT,   // (N*B, HW, 32) channels-last
    const float* __restrict__ refT,   // (B,   HW, 32) channels-last
    const float* __restrict__ depT,   // (B,   HW, 32) depth-last
    const float* __restrict__ mats,   // (B*N, 12) rot row-major + trans
    const float* __restrict__ regw,   // (8,)
    const float* __restrict__ regb,   // (1,)
    float* __restrict__ out)          // [B*HW depth][B*D*HW attn]
{
    int tid = threadIdx.x;
    int seg = tid >> 5;
    int d   = tid & 31;
    int p   = blockIdx.x * 8 + seg;        // global pixel 0..B*HW-1
    int b   = p / HW;
    int rem = p - b * HW;
    int y   = rem / WW;
    int x   = rem - y * WW;
    float fx = (float)x, fy = (float)y;

    // ref feature for this pixel: 8 groups x float4 (broadcast within segment)
    const float4* rp = (const float4*)(refT + (size_t)p * 32);
    float4 R[8];
#pragma unroll
    for (int g = 0; g < 8; g++) R[g] = rp[g];

    float dep = depT[(size_t)p * 32 + d];

    float rw[8];
#pragma unroll
    for (int g = 0; g < 8; g++) rw[g] = regw[g];
    float rb = regb[0];

    float cf[8];
#pragma unroll
    for (int g = 0; g < 8; g++) cf[g] = 0.f;
    float cwsum = 1e-8f;

    for (int n = 0; n < NN; n++) {
        const float* Mp = mats + (size_t)(b * NN + n) * 12;
        float r00 = Mp[0], r01 = Mp[1], r02 = Mp[2];
        float r10 = Mp[3], r11 = Mp[4], r12 = Mp[5];
        float r20 = Mp[6], r21 = Mp[7], r22 = Mp[8];
        float t0 = Mp[9], t1 = Mp[10], t2 = Mp[11];

        float px = (r00 * fx + r01 * fy + r02) * dep + t0;
        float py = (r10 * fx + r11 * fy + r12) * dep + t1;
        float pz = (r20 * fx + r21 * fy + r22) * dep + t2;
        float z  = (pz == 0.f) ? 1e-9f : pz;
        float gx = px / z, gy = py / z;

        float x0f = floorf(gx), y0f = floorf(gy);
        float wx = gx - x0f, wy = gy - y0f;
        bool vx0 = (x0f >= 0.f)  && (x0f <= (float)(WW - 1));
        bool vx1 = (x0f >= -1.f) && (x0f <= (float)(WW - 2));
        bool vy0 = (y0f >= 0.f)  && (y0f <= (float)(HH - 1));
        bool vy1 = (y0f >= -1.f) && (y0f <= (float)(HH - 2));
        // ternary (not multiply) so Inf/NaN coords can't poison via NaN*0
        float w00 = (vx0 && vy0) ? (1.f - wx) * (1.f - wy) : 0.f;
        float w10 = (vx1 && vy0) ? wx * (1.f - wy)         : 0.f;
        float w01 = (vx0 && vy1) ? (1.f - wx) * wy         : 0.f;
        float w11 = (vx1 && vy1) ? wx * wy                 : 0.f;

        int xi0 = (int)fminf(fmaxf(x0f,        0.f), (float)(WW - 1));
        int xi1 = (int)fminf(fmaxf(x0f + 1.f,  0.f), (float)(WW - 1));
        int yi0 = (int)fminf(fmaxf(y0f,        0.f), (float)(HH - 1));
        int yi1 = (int)fminf(fmaxf(y0f + 1.f,  0.f), (float)(HH - 1));

        const float* S = srcT + (size_t)(n * BB + b) * (32 * HW);
        const float4* p00 = (const float4*)(S + (size_t)(yi0 * WW + xi0) * 32);
        const float4* p10 = (const float4*)(S + (size_t)(yi0 * WW + xi1) * 32);
        const float4* p01 = (const float4*)(S + (size_t)(yi1 * WW + xi0) * 32);
        const float4* p11 = (const float4*)(S + (size_t)(yi1 * WW + xi1) * 32);

        float cor[8];
#pragma unroll
        for (int g = 0; g < 8; g++) {
            float4 a = p00[g], bq = p10[g], c = p01[g], e = p11[g];
            float d00 = a.x  * R[g].x + a.y  * R[g].y + a.z  * R[g].z + a.w  * R[g].w;
            float d10 = bq.x * R[g].x + bq.y * R[g].y + bq.z * R[g].z + bq.w * R[g].w;
            float d01 = c.x  * R[g].x + c.y  * R[g].y + c.z  * R[g].z + c.w  * R[g].w;
            float d11 = e.x  * R[g].x + e.y  * R[g].y + e.z  * R[g].z + e.w  * R[g].w;
            cor[g] = w00 * d00 + w10 * d10 + w01 * d01 + w11 * d11;
        }

        float lsum = ((cor[0] + cor[1]) + (cor[2] + cor[3])) +
                     ((cor[4] + cor[5]) + (cor[6] + cor[7]));
        // mean over C//G=4 (0.25) then / attn_temp=2  -> *0.125
        float logit = lsum * 0.125f;

        // softmax over the 32-lane depth segment
        float m = logit;
#pragma unroll
        for (int s = 16; s; s >>= 1) m = fmaxf(m, __shfl_xor(m, s, 32));
        float e1 = __expf(logit - m);
        float ssum = e1;
#pragma unroll
        for (int s = 16; s; s >>= 1) ssum += __shfl_xor(ssum, s, 32);
        float cw = e1 / ssum * 0.17677669529663687f;   // / sqrt(C=32)
        cwsum += cw;
        float cw25 = cw * 0.25f;                        // fold mean(2) factor
#pragma unroll
        for (int g = 0; g < 8; g++) cf[g] += cw25 * cor[g];
    }

    // final logits: (sum_g cf[g]*reg_w[g]) / cwsum + reg_b
    float s2 = 0.f;
#pragma unroll
    for (int g = 0; g < 8; g++) s2 += cf[g] * rw[g];
    float logit2 = s2 / cwsum + rb;

    float m2 = logit2;
#pragma unroll
    for (int s = 16; s; s >>= 1) m2 = fmaxf(m2, __shfl_xor(m2, s, 32));
    float e2 = __expf(logit2 - m2);
    float ss2 = e2;
#pragma unroll
    for (int s = 16; s; s >>= 1) ss2 += __shfl_xor(ss2, s, 32);
    float aw = e2 / ss2;

    // attn_weight: (B, D, H, W) after depth output (B, H, W)
    out[(size_t)BB * HW + (size_t)(b * DD + d) * HW + rem] = aw;

    // argmax over d (first-max tie-break), winner writes depth
    float bv = logit2; int bi = d;
#pragma unroll
    for (int s = 16; s; s >>= 1) {
        float ov = __shfl_xor(bv, s, 32);
        int   oi = __shfl_xor(bi, s, 32);
        if (ov > bv || (ov == bv && oi < bi)) { bv = ov; bi = oi; }
    }
    if (d == bi) out[p] = dep;
}

// ---------------------------------------------------------------------------
extern "C" void kernel_launch(void* const* d_in, const int* in_sizes, int n_in,
                              void* d_out, int out_size, void* d_ws, size_t ws_size,
                              hipStream_t stream) {
    const float* ref   = (const float*)d_in[0];  // (B,C,H,W)
    const float* src   = (const float*)d_in[1];  // (N,B,C,H,W)
    const float* proj  = (const float*)d_in[2];  // (B,N+1,2,4,4)
    const float* depth = (const float*)d_in[3];  // (B,D,H,W)
    const float* regw  = (const float*)d_in[4];  // (8,)
    const float* regb  = (const float*)d_in[5];  // (1,)
    float* out = (float*)d_out;

    float* ws   = (float*)d_ws;
    float* mats = ws;                       // 96 floats (pad to 256)
    float* srcT = ws + 256;                 // N*B*HW*32 = 5,242,880
    float* refT = srcT + (size_t)NN * BB * HW * 32;  // B*HW*32 = 1,310,720
    float* depT = refT + (size_t)BB * HW * 32;       // B*HW*32 = 1,310,720

    mat_kernel<<<1, 64, 0, stream>>>(proj, mats);
    transpose32<<<dim3(HW / 32, NN * BB), 256, 0, stream>>>(src, srcT);
    transpose32<<<dim3(HW / 32, BB), 256, 0, stream>>>(ref, refT);
    transpose32<<<dim3(HW / 32, BB), 256, 0, stream>>>(depth, depT);

    main_kernel<<<(BB * HW) / 8, 256, 0, stream>>>(srcT, refT, depT, mats,
                                                   regw, regb, out);
}

// Round 3
// 245.834 us; speedup vs baseline: 1.2379x; 1.2379x over previous
//
#include <hip/hip_runtime.h>
#include <hip/hip_bf16.h>
#include <math.h>

// Problem constants (from reference setup_inputs)
#define BB 2
#define CC 32
#define HH 128
#define WW 160
#define DD 32
#define NN 4
#define HW (HH * WW)        // 20480
#define GG 8

// ---------------------------------------------------------------------------
// Kernel 1: per-(b,src) projection matrices (FP64 Gauss-Jordan, 8 threads).
// ---------------------------------------------------------------------------
__global__ void mat_kernel(const float* __restrict__ proj, float* __restrict__ mats) {
    int t = threadIdx.x;
    if (t >= BB * NN) return;
    int b = t >> 2, n = t & 3;
    const float* Er = proj + ((size_t)(b * (NN + 1) + 0) * 2 + 0) * 16;
    const float* Kr = proj + ((size_t)(b * (NN + 1) + 0) * 2 + 1) * 16;
    const float* Es = proj + ((size_t)(b * (NN + 1) + n + 1) * 2 + 0) * 16;
    const float* Ks = proj + ((size_t)(b * (NN + 1) + n + 1) * 2 + 1) * 16;

    double A[4][4], Bm[4][4];
    for (int r = 0; r < 4; r++)
        for (int c = 0; c < 4; c++) {
            if (r < 3) {
                A[r][c]  = (double)Kr[r*4+0]*Er[0*4+c] + (double)Kr[r*4+1]*Er[1*4+c] + (double)Kr[r*4+2]*Er[2*4+c];
                Bm[r][c] = (double)Ks[r*4+0]*Es[0*4+c] + (double)Ks[r*4+1]*Es[1*4+c] + (double)Ks[r*4+2]*Es[2*4+c];
            } else {
                A[r][c]  = (double)Er[12 + c];
                Bm[r][c] = (double)Es[12 + c];
            }
        }
    double M[4][8];
    for (int i = 0; i < 4; i++)
        for (int j = 0; j < 4; j++) { M[i][j] = A[i][j]; M[i][4+j] = (i == j) ? 1.0 : 0.0; }
    for (int col = 0; col < 4; col++) {
        int piv = col;
        for (int r = col + 1; r < 4; r++)
            if (fabs(M[r][col]) > fabs(M[piv][col])) piv = r;
        if (piv != col)
            for (int j = 0; j < 8; j++) { double tmp = M[col][j]; M[col][j] = M[piv][j]; M[piv][j] = tmp; }
        double pv = M[col][col];
        for (int j = 0; j < 8; j++) M[col][j] /= pv;
        for (int r = 0; r < 4; r++) {
            if (r == col) continue;
            double f = M[r][col];
            for (int j = 0; j < 8; j++) M[r][j] -= f * M[col][j];
        }
    }
    float* o = mats + t * 12;
    for (int i = 0; i < 3; i++) {
        double p0 = 0, p1 = 0, p2 = 0, p3 = 0;
        for (int k = 0; k < 4; k++) {
            p0 += Bm[i][k] * M[k][4+0];
            p1 += Bm[i][k] * M[k][4+1];
            p2 += Bm[i][k] * M[k][4+2];
            p3 += Bm[i][k] * M[k][4+3];
        }
        o[i*3+0] = (float)p0; o[i*3+1] = (float)p1; o[i*3+2] = (float)p2;
        o[9 + i] = (float)p3;
    }
}

// ---------------------------------------------------------------------------
// Kernel 2: merged transpose [32][HW] -> [HW][32]; slabs 0-7 = src, 8-9 = ref.
// ---------------------------------------------------------------------------
__global__ __launch_bounds__(256) void prep_transpose(const float* __restrict__ src,
                                                      const float* __restrict__ ref,
                                                      float* __restrict__ srcT,
                                                      float* __restrict__ refT) {
    __shared__ float t[32][33];
    int slab = blockIdx.y;
    const float* ip;
    float* op;
    if (slab < 8) { ip = src + (size_t)slab * 32 * HW; op = srcT + (size_t)slab * 32 * HW; }
    else          { ip = ref + (size_t)(slab - 8) * 32 * HW; op = refT + (size_t)(slab - 8) * 32 * HW; }
    int hw0 = blockIdx.x * 32;
    int tx = threadIdx.x & 31, ty = threadIdx.x >> 5;
#pragma unroll
    for (int i = 0; i < 4; i++) {
        int c = ty + i * 8;
        t[c][tx] = ip[(size_t)c * HW + hw0 + tx];
    }
    __syncthreads();
#pragma unroll
    for (int i = 0; i < 4; i++) {
        int hl = ty + i * 8;
        op[(size_t)(hw0 + hl) * 32 + tx] = t[tx][hl];
    }
}

// ---------------------------------------------------------------------------
// Kernel 3: main fused kernel. Block = 256 threads = one ref pixel.
// Thread (d,g): d = tid>>3 (depth 0..31), g = tid&7 (channel group).
// D-reductions go through explicit LDS arrays (sL, sE) + octet-only (xor
// 1/2/4) butterflies. Exactly 2 __syncthreads() in the whole kernel.
// ---------------------------------------------------------------------------
__global__ __launch_bounds__(256) void main_kernel(
    const float* __restrict__ srcT,   // (N*B, HW, 32) channels-last
    const float* __restrict__ refT,   // (B,   HW, 32) channels-last
    const float* __restrict__ depth,  // (B, D, H, W) original layout
    const float* __restrict__ mats,   // (B*N, 12) rot row-major + trans
    const float* __restrict__ regw,   // (8,)
    const float* __restrict__ regb,   // (1,)
    float* __restrict__ out)          // [B*HW depth][B*D*HW attn]
{
    int tid = threadIdx.x;
    int g  = tid & 7;
    int d  = tid >> 3;      // 0..31

    int p   = blockIdx.x;   // global pixel 0..B*HW-1
    int b   = p / HW;
    int rem = p - b * HW;
    int y   = rem / WW;
    int x   = rem - y * WW;
    float fx = (float)x, fy = (float)y;

    // this thread's group of the ref feature (one float4)
    float4 R = *(const float4*)(refT + (size_t)p * 32 + g * 4);
    float dep = depth[((size_t)(b * DD + d) * HH + y) * WW + x];
    float rwg = regw[g];
    float rb  = regb[0];

    __shared__ float sL[NN][DD];   // per-source logits over depth
    __shared__ float sE[DD];       // final logits over depth

    float cor[NN];
    float logit[NN];

    // ---- Phase 1: gathers + dots + octet g-sum; no barriers
#pragma unroll
    for (int n = 0; n < NN; n++) {
        const float* Mp = mats + (size_t)(b * NN + n) * 12;
        float ax = Mp[0] * fx + Mp[1] * fy + Mp[2];
        float ay = Mp[3] * fx + Mp[4] * fy + Mp[5];
        float az = Mp[6] * fx + Mp[7] * fy + Mp[8];
        float px = ax * dep + Mp[9];
        float py = ay * dep + Mp[10];
        float pz = az * dep + Mp[11];
        float z  = (pz == 0.f) ? 1e-9f : pz;
        float gx = px / z, gy = py / z;

        float x0f = floorf(gx), y0f = floorf(gy);
        float wx = gx - x0f, wy = gy - y0f;
        bool vx0 = (x0f >= 0.f)  && (x0f <= (float)(WW - 1));
        bool vx1 = (x0f >= -1.f) && (x0f <= (float)(WW - 2));
        bool vy0 = (y0f >= 0.f)  && (y0f <= (float)(HH - 1));
        bool vy1 = (y0f >= -1.f) && (y0f <= (float)(HH - 2));
        float w00 = (vx0 && vy0) ? (1.f - wx) * (1.f - wy) : 0.f;
        float w10 = (vx1 && vy0) ? wx * (1.f - wy)         : 0.f;
        float w01 = (vx0 && vy1) ? (1.f - wx) * wy         : 0.f;
        float w11 = (vx1 && vy1) ? wx * wy                 : 0.f;

        int xi0 = (int)fminf(fmaxf(x0f,       0.f), (float)(WW - 1));
        int xi1 = (int)fminf(fmaxf(x0f + 1.f, 0.f), (float)(WW - 1));
        int yi0 = (int)fminf(fmaxf(y0f,       0.f), (float)(HH - 1));
        int yi1 = (int)fminf(fmaxf(y0f + 1.f, 0.f), (float)(HH - 1));

        const float4* S4 = (const float4*)(srcT + (size_t)(n * BB + b) * (32 * HW));
        float4 a  = S4[(size_t)(yi0 * WW + xi0) * 8 + g];
        float4 bq = S4[(size_t)(yi0 * WW + xi1) * 8 + g];
        float4 c  = S4[(size_t)(yi1 * WW + xi0) * 8 + g];
        float4 e  = S4[(size_t)(yi1 * WW + xi1) * 8 + g];

        float d00 = a.x  * R.x + a.y  * R.y + a.z  * R.z + a.w  * R.w;
        float d10 = bq.x * R.x + bq.y * R.y + bq.z * R.z + bq.w * R.w;
        float d01 = c.x  * R.x + c.y  * R.y + c.z  * R.z + c.w  * R.w;
        float d11 = e.x  * R.x + e.y  * R.y + e.z  * R.z + e.w  * R.w;
        float cr = w00 * d00 + w10 * d10 + w01 * d01 + w11 * d11;
        cor[n] = cr;

        // sum over the 8 channel-groups (octet butterfly; lane-invariant)
        float ls = cr;
        ls += __shfl_xor(ls, 1);
        ls += __shfl_xor(ls, 2);
        ls += __shfl_xor(ls, 4);
        logit[n] = ls * 0.125f;   // mean over C//G=4 then / attn_temp=2
        if (g == 0) sL[n][d] = logit[n];
    }
    __syncthreads();   // sL fully populated

    // ---- Phase 2: per-source softmax over D from sL (chunked + octet bfly)
    float cf = 0.f;
    float cwsum = 1e-8f;
#pragma unroll
    for (int n = 0; n < NN; n++) {
        float l0 = sL[n][g * 4 + 0];
        float l1 = sL[n][g * 4 + 1];
        float l2 = sL[n][g * 4 + 2];
        float l3 = sL[n][g * 4 + 3];
        float lm = fmaxf(fmaxf(l0, l1), fmaxf(l2, l3));
        lm = fmaxf(lm, __shfl_xor(lm, 1));
        lm = fmaxf(lm, __shfl_xor(lm, 2));
        lm = fmaxf(lm, __shfl_xor(lm, 4));
        float ts = __expf(l0 - lm) + __expf(l1 - lm) + __expf(l2 - lm) + __expf(l3 - lm);
        ts += __shfl_xor(ts, 1);
        ts += __shfl_xor(ts, 2);
        ts += __shfl_xor(ts, 4);
        float e1 = __expf(logit[n] - lm);          // logit[n] == sL[n][d] bit-exact
        float cw = e1 / ts * 0.17677669529663687f; // / sqrt(C=32)
        cwsum += cw;
        cf += cw * cor[n] * 0.25f;                 // fold mean(C//G=4) factor
    }

    // ---- Epilogue: reg projection -> sE, softmax over D, argmax depth
    float v = cf * rwg;
    v += __shfl_xor(v, 1);
    v += __shfl_xor(v, 2);
    v += __shfl_xor(v, 4);
    float logit2 = v / cwsum + rb;                 // identical across octet
    if (g == 0) sE[d] = logit2;
    __syncthreads();   // sE fully populated

    float q0 = sE[g * 4 + 0];
    float q1 = sE[g * 4 + 1];
    float q2 = sE[g * 4 + 2];
    float q3 = sE[g * 4 + 3];
    float m2 = fmaxf(fmaxf(q0, q1), fmaxf(q2, q3));
    m2 = fmaxf(m2, __shfl_xor(m2, 1));
    m2 = fmaxf(m2, __shfl_xor(m2, 2));
    m2 = fmaxf(m2, __shfl_xor(m2, 4));
    float t2 = __expf(q0 - m2) + __expf(q1 - m2) + __expf(q2 - m2) + __expf(q3 - m2);
    t2 += __shfl_xor(t2, 1);
    t2 += __shfl_xor(t2, 2);
    t2 += __shfl_xor(t2, 4);
    float aw = __expf(logit2 - m2) / t2;

    if (g == 0)
        out[(size_t)BB * HW + (size_t)(b * DD + d) * HW + rem] = aw;

    // argmax over D (first-max semantics): strict-> in chunk scan,
    // (gt || (eq && idx<)) in the octet combine. Lane-invariant result.
    float bv = q0; int bi = g * 4;
    if (q1 > bv) { bv = q1; bi = g * 4 + 1; }
    if (q2 > bv) { bv = q2; bi = g * 4 + 2; }
    if (q3 > bv) { bv = q3; bi = g * 4 + 3; }
#pragma unroll
    for (int s = 1; s <= 4; s <<= 1) {
        float ov = __shfl_xor(bv, s);
        int   oi = __shfl_xor(bi, s);
        if (ov > bv || (ov == bv && oi < bi)) { bv = ov; bi = oi; }
    }
    if (d == bi && g == 0) out[p] = dep;
}

// ---------------------------------------------------------------------------
extern "C" void kernel_launch(void* const* d_in, const int* in_sizes, int n_in,
                              void* d_out, int out_size, void* d_ws, size_t ws_size,
                              hipStream_t stream) {
    const float* ref   = (const float*)d_in[0];  // (B,C,H,W)
    const float* src   = (const float*)d_in[1];  // (N,B,C,H,W)
    const float* proj  = (const float*)d_in[2];  // (B,N+1,2,4,4)
    const float* depth = (const float*)d_in[3];  // (B,D,H,W)
    const float* regw  = (const float*)d_in[4];  // (8,)
    const float* regb  = (const float*)d_in[5];  // (1,)
    float* out = (float*)d_out;

    float* ws   = (float*)d_ws;
    float* mats = ws;                                 // 96 floats (pad to 256)
    float* srcT = ws + 256;                           // N*B*HW*32 = 5,242,880
    float* refT = srcT + (size_t)NN * BB * HW * 32;   // B*HW*32 = 1,310,720

    mat_kernel<<<1, 64, 0, stream>>>(proj, mats);
    prep_transpose<<<dim3(HW / 32, 10), 256, 0, stream>>>(src, ref, srcT, refT);
    main_kernel<<<BB * HW, 256, 0, stream>>>(srcT, refT, depth, mats,
                                             regw, regb, out);
}

// Round 4
// 239.394 us; speedup vs baseline: 1.2712x; 1.0269x over previous
//
#include <hip/hip_runtime.h>
#include <hip/hip_bf16.h>
#include <math.h>

// Problem constants (from reference setup_inputs)
#define BB 2
#define CC 32
#define HH 128
#define WW 160
#define DD 32
#define NN 4
#define HW (HH * WW)        // 20480
#define GG 8

// ---------------------------------------------------------------------------
// Device helper: per-(b,src) projection matrices (FP64 Gauss-Jordan).
// Executed by threads 0..7 of one block of the prep kernel.
// ---------------------------------------------------------------------------
__device__ void compute_mats(int t, const float* __restrict__ proj,
                             float* __restrict__ mats) {
    int b = t >> 2, n = t & 3;
    const float* Er = proj + ((size_t)(b * (NN + 1) + 0) * 2 + 0) * 16;
    const float* Kr = proj + ((size_t)(b * (NN + 1) + 0) * 2 + 1) * 16;
    const float* Es = proj + ((size_t)(b * (NN + 1) + n + 1) * 2 + 0) * 16;
    const float* Ks = proj + ((size_t)(b * (NN + 1) + n + 1) * 2 + 1) * 16;

    double A[4][4], Bm[4][4];
    for (int r = 0; r < 4; r++)
        for (int c = 0; c < 4; c++) {
            if (r < 3) {
                A[r][c]  = (double)Kr[r*4+0]*Er[0*4+c] + (double)Kr[r*4+1]*Er[1*4+c] + (double)Kr[r*4+2]*Er[2*4+c];
                Bm[r][c] = (double)Ks[r*4+0]*Es[0*4+c] + (double)Ks[r*4+1]*Es[1*4+c] + (double)Ks[r*4+2]*Es[2*4+c];
            } else {
                A[r][c]  = (double)Er[12 + c];
                Bm[r][c] = (double)Es[12 + c];
            }
        }
    double M[4][8];
    for (int i = 0; i < 4; i++)
        for (int j = 0; j < 4; j++) { M[i][j] = A[i][j]; M[i][4+j] = (i == j) ? 1.0 : 0.0; }
    for (int col = 0; col < 4; col++) {
        int piv = col;
        for (int r = col + 1; r < 4; r++)
            if (fabs(M[r][col]) > fabs(M[piv][col])) piv = r;
        if (piv != col)
            for (int j = 0; j < 8; j++) { double tmp = M[col][j]; M[col][j] = M[piv][j]; M[piv][j] = tmp; }
        double pv = M[col][col];
        for (int j = 0; j < 8; j++) M[col][j] /= pv;
        for (int r = 0; r < 4; r++) {
            if (r == col) continue;
            double f = M[r][col];
            for (int j = 0; j < 8; j++) M[r][j] -= f * M[col][j];
        }
    }
    float* o = mats + t * 12;
    for (int i = 0; i < 3; i++) {
        double p0 = 0, p1 = 0, p2 = 0, p3 = 0;
        for (int k = 0; k < 4; k++) {
            p0 += Bm[i][k] * M[k][4+0];
            p1 += Bm[i][k] * M[k][4+1];
            p2 += Bm[i][k] * M[k][4+2];
            p3 += Bm[i][k] * M[k][4+3];
        }
        o[i*3+0] = (float)p0; o[i*3+1] = (float)p1; o[i*3+2] = (float)p2;
        o[9 + i] = (float)p3;
    }
}

// ---------------------------------------------------------------------------
// Kernel 1: merged transpose [32][HW] -> [HW][32]; slabs 0-7 = src, 8-9 = ref.
// Block (0,0) additionally computes the 8 projection matrices (tid<8).
// ---------------------------------------------------------------------------
__global__ __launch_bounds__(256) void prep_transpose(const float* __restrict__ src,
                                                      const float* __restrict__ ref,
                                                      const float* __restrict__ proj,
                                                      float* __restrict__ srcT,
                                                      float* __restrict__ refT,
                                                      float* __restrict__ mats) {
    if (blockIdx.x == 0 && blockIdx.y == 0 && threadIdx.x < 8)
        compute_mats(threadIdx.x, proj, mats);

    __shared__ float t[32][33];
    int slab = blockIdx.y;
    const float* ip;
    float* op;
    if (slab < 8) { ip = src + (size_t)slab * 32 * HW; op = srcT + (size_t)slab * 32 * HW; }
    else          { ip = ref + (size_t)(slab - 8) * 32 * HW; op = refT + (size_t)(slab - 8) * 32 * HW; }
    int hw0 = blockIdx.x * 32;
    int tx = threadIdx.x & 31, ty = threadIdx.x >> 5;
#pragma unroll
    for (int i = 0; i < 4; i++) {
        int c = ty + i * 8;
        t[c][tx] = ip[(size_t)c * HW + hw0 + tx];
    }
    __syncthreads();
#pragma unroll
    for (int i = 0; i < 4; i++) {
        int hl = ty + i * 8;
        op[(size_t)(hw0 + hl) * 32 + tx] = t[tx][hl];
    }
}

// ---------------------------------------------------------------------------
// Kernel 2: main fused kernel. Block = 256 threads = one ref pixel.
// Thread (d,g): d = tid>>3 (depth 0..31), g = tid&7 (channel group).
// Homography per (n,d) computed ONCE per octet-slot: every lane computes the
// n0 = tid&3 homography at its own d; phase 1 pulls the 4 weights + 4 tap
// indices from lane (tid&56)|n via wave-synchronous shuffles (bit-exact same
// values as local recompute). Downstream dataflow identical to round 3.
// ---------------------------------------------------------------------------
__global__ __launch_bounds__(256) void main_kernel(
    const float* __restrict__ srcT,   // (N*B, HW, 32) channels-last
    const float* __restrict__ refT,   // (B,   HW, 32) channels-last
    const float* __restrict__ depth,  // (B, D, H, W) original layout
    const float* __restrict__ mats,   // (B*N, 12) rot row-major + trans
    const float* __restrict__ regw,   // (8,)
    const float* __restrict__ regb,   // (1,)
    float* __restrict__ out)          // [B*HW depth][B*D*HW attn]
{
    int tid = threadIdx.x;
    int g  = tid & 7;
    int d  = tid >> 3;      // 0..31

    int p   = blockIdx.x;   // global pixel 0..B*HW-1
    int b   = p / HW;
    int rem = p - b * HW;
    int y   = rem / WW;
    int x   = rem - y * WW;
    float fx = (float)x, fy = (float)y;

    // this thread's group of the ref feature (one float4)
    float4 R = *(const float4*)(refT + (size_t)p * 32 + g * 4);
    float dep = depth[((size_t)(b * DD + d) * HH + y) * WW + x];
    float rwg = regw[g];
    float rb  = regb[0];

    __shared__ float sL[NN][DD];   // per-source logits over depth
    __shared__ float sE[DD];       // final logits over depth

    // ---- Phase 0: one homography per lane, for source n0 = tid&3 at depth d
    float W00, W10, W01, W11;
    int   I00, I10, I01, I11;
    {
        int n0 = tid & 3;
        const float* Mp = mats + (size_t)(b * NN + n0) * 12;
        float ax = Mp[0] * fx + Mp[1] * fy + Mp[2];
        float ay = Mp[3] * fx + Mp[4] * fy + Mp[5];
        float az = Mp[6] * fx + Mp[7] * fy + Mp[8];
        float px = ax * dep + Mp[9];
        float py = ay * dep + Mp[10];
        float pz = az * dep + Mp[11];
        float z  = (pz == 0.f) ? 1e-9f : pz;
        float gx = px / z, gy = py / z;

        float x0f = floorf(gx), y0f = floorf(gy);
        float wx = gx - x0f, wy = gy - y0f;
        bool vx0 = (x0f >= 0.f)  && (x0f <= (float)(WW - 1));
        bool vx1 = (x0f >= -1.f) && (x0f <= (float)(WW - 2));
        bool vy0 = (y0f >= 0.f)  && (y0f <= (float)(HH - 1));
        bool vy1 = (y0f >= -1.f) && (y0f <= (float)(HH - 2));
        W00 = (vx0 && vy0) ? (1.f - wx) * (1.f - wy) : 0.f;
        W10 = (vx1 && vy0) ? wx * (1.f - wy)         : 0.f;
        W01 = (vx0 && vy1) ? (1.f - wx) * wy         : 0.f;
        W11 = (vx1 && vy1) ? wx * wy                 : 0.f;

        int xi0 = (int)fminf(fmaxf(x0f,       0.f), (float)(WW - 1));
        int xi1 = (int)fminf(fmaxf(x0f + 1.f, 0.f), (float)(WW - 1));
        int yi0 = (int)fminf(fmaxf(y0f,       0.f), (float)(HH - 1));
        int yi1 = (int)fminf(fmaxf(y0f + 1.f, 0.f), (float)(HH - 1));
        I00 = yi0 * WW + xi0;
        I10 = yi0 * WW + xi1;
        I01 = yi1 * WW + xi0;
        I11 = yi1 * WW + xi1;
    }

    float cor[NN];
    float logit[NN];

    // ---- Phase 1: gathers + dots + octet g-sum; no barriers
#pragma unroll
    for (int n = 0; n < NN; n++) {
        int src_lane = (tid & 56) | n;     // lane holding (n, my d)
        float w00 = __shfl(W00, src_lane);
        float w10 = __shfl(W10, src_lane);
        float w01 = __shfl(W01, src_lane);
        float w11 = __shfl(W11, src_lane);
        int   i00 = __shfl(I00, src_lane);
        int   i10 = __shfl(I10, src_lane);
        int   i01 = __shfl(I01, src_lane);
        int   i11 = __shfl(I11, src_lane);

        const float4* S4 = (const float4*)(srcT + (size_t)(n * BB + b) * (32 * HW));
        float4 a  = S4[(size_t)i00 * 8 + g];
        float4 bq = S4[(size_t)i10 * 8 + g];
        float4 c  = S4[(size_t)i01 * 8 + g];
        float4 e  = S4[(size_t)i11 * 8 + g];

        float d00 = a.x  * R.x + a.y  * R.y + a.z  * R.z + a.w  * R.w;
        float d10 = bq.x * R.x + bq.y * R.y + bq.z * R.z + bq.w * R.w;
        float d01 = c.x  * R.x + c.y  * R.y + c.z  * R.z + c.w  * R.w;
        float d11 = e.x  * R.x + e.y  * R.y + e.z  * R.z + e.w  * R.w;
        float cr = w00 * d00 + w10 * d10 + w01 * d01 + w11 * d11;
        cor[n] = cr;

        // sum over the 8 channel-groups (octet butterfly; lane-invariant)
        float ls = cr;
        ls += __shfl_xor(ls, 1);
        ls += __shfl_xor(ls, 2);
        ls += __shfl_xor(ls, 4);
        logit[n] = ls * 0.125f;   // mean over C//G=4 then / attn_temp=2
        if (g == 0) sL[n][d] = logit[n];
    }
    __syncthreads();   // sL fully populated

    // ---- Phase 2: per-source softmax over D from sL (chunked + octet bfly)
    float cf = 0.f;
    float cwsum = 1e-8f;
#pragma unroll
    for (int n = 0; n < NN; n++) {
        float l0 = sL[n][g * 4 + 0];
        float l1 = sL[n][g * 4 + 1];
        float l2 = sL[n][g * 4 + 2];
        float l3 = sL[n][g * 4 + 3];
        float lm = fmaxf(fmaxf(l0, l1), fmaxf(l2, l3));
        lm = fmaxf(lm, __shfl_xor(lm, 1));
        lm = fmaxf(lm, __shfl_xor(lm, 2));
        lm = fmaxf(lm, __shfl_xor(lm, 4));
        float ts = __expf(l0 - lm) + __expf(l1 - lm) + __expf(l2 - lm) + __expf(l3 - lm);
        ts += __shfl_xor(ts, 1);
        ts += __shfl_xor(ts, 2);
        ts += __shfl_xor(ts, 4);
        float e1 = __expf(logit[n] - lm);          // logit[n] == sL[n][d] bit-exact
        float cw = e1 / ts * 0.17677669529663687f; // / sqrt(C=32)
        cwsum += cw;
        cf += cw * cor[n] * 0.25f;                 // fold mean(C//G=4) factor
    }

    // ---- Epilogue: reg projection -> sE, softmax over D, argmax depth
    float v = cf * rwg;
    v += __shfl_xor(v, 1);
    v += __shfl_xor(v, 2);
    v += __shfl_xor(v, 4);
    float logit2 = v / cwsum + rb;                 // identical across octet
    if (g == 0) sE[d] = logit2;
    __syncthreads();   // sE fully populated

    float q0 = sE[g * 4 + 0];
    float q1 = sE[g * 4 + 1];
    float q2 = sE[g * 4 + 2];
    float q3 = sE[g * 4 + 3];
    float m2 = fmaxf(fmaxf(q0, q1), fmaxf(q2, q3));
    m2 = fmaxf(m2, __shfl_xor(m2, 1));
    m2 = fmaxf(m2, __shfl_xor(m2, 2));
    m2 = fmaxf(m2, __shfl_xor(m2, 4));
    float t2 = __expf(q0 - m2) + __expf(q1 - m2) + __expf(q2 - m2) + __expf(q3 - m2);
    t2 += __shfl_xor(t2, 1);
    t2 += __shfl_xor(t2, 2);
    t2 += __shfl_xor(t2, 4);
    float aw = __expf(logit2 - m2) / t2;

    if (g == 0)
        out[(size_t)BB * HW + (size_t)(b * DD + d) * HW + rem] = aw;

    // argmax over D (first-max semantics): strict-> in chunk scan,
    // (gt || (eq && idx<)) in the octet combine. Lane-invariant result.
    float bv = q0; int bi = g * 4;
    if (q1 > bv) { bv = q1; bi = g * 4 + 1; }
    if (q2 > bv) { bv = q2; bi = g * 4 + 2; }
    if (q3 > bv) { bv = q3; bi = g * 4 + 3; }
#pragma unroll
    for (int s = 1; s <= 4; s <<= 1) {
        float ov = __shfl_xor(bv, s);
        int   oi = __shfl_xor(bi, s);
        if (ov > bv || (ov == bv && oi < bi)) { bv = ov; bi = oi; }
    }
    if (d == bi && g == 0) out[p] = dep;
}

// ---------------------------------------------------------------------------
extern "C" void kernel_launch(void* const* d_in, const int* in_sizes, int n_in,
                              void* d_out, int out_size, void* d_ws, size_t ws_size,
                              hipStream_t stream) {
    const float* ref   = (const float*)d_in[0];  // (B,C,H,W)
    const float* src   = (const float*)d_in[1];  // (N,B,C,H,W)
    const float* proj  = (const float*)d_in[2];  // (B,N+1,2,4,4)
    const float* depth = (const float*)d_in[3];  // (B,D,H,W)
    const float* regw  = (const float*)d_in[4];  // (8,)
    const float* regb  = (const float*)d_in[5];  // (1,)
    float* out = (float*)d_out;

    float* ws   = (float*)d_ws;
    float* mats = ws;                                 // 96 floats (pad to 256)
    float* srcT = ws + 256;                           // N*B*HW*32 = 5,242,880
    float* refT = srcT + (size_t)NN * BB * HW * 32;   // B*HW*32 = 1,310,720

    prep_transpose<<<dim3(HW / 32, 10), 256, 0, stream>>>(src, ref, proj,
                                                          srcT, refT, mats);
    main_kernel<<<BB * HW, 256, 0, stream>>>(srcT, refT, depth, mats,
                                             regw, regb, out);
}

// Round 5
// 200.069 us; speedup vs baseline: 1.5210x; 1.1966x over previous
//
#include <hip/hip_runtime.h>
#include <hip/hip_bf16.h>
#include <math.h>

// Problem constants (from reference setup_inputs)
#define BB 2
#define CC 32
#define HH 128
#define WW 160
#define DD 32
#define NN 4
#define HW (HH * WW)        // 20480
#define GG 8

// ---------------------------------------------------------------------------
// Device helper: per-(b,src) projection matrices (FP64 Gauss-Jordan).
// Executed by threads 0..7 of one block of the prep kernel.
// ---------------------------------------------------------------------------
__device__ void compute_mats(int t, const float* __restrict__ proj,
                             float* __restrict__ mats) {
    int b = t >> 2, n = t & 3;
    const float* Er = proj + ((size_t)(b * (NN + 1) + 0) * 2 + 0) * 16;
    const float* Kr = proj + ((size_t)(b * (NN + 1) + 0) * 2 + 1) * 16;
    const float* Es = proj + ((size_t)(b * (NN + 1) + n + 1) * 2 + 0) * 16;
    const float* Ks = proj + ((size_t)(b * (NN + 1) + n + 1) * 2 + 1) * 16;

    double A[4][4], Bm[4][4];
    for (int r = 0; r < 4; r++)
        for (int c = 0; c < 4; c++) {
            if (r < 3) {
                A[r][c]  = (double)Kr[r*4+0]*Er[0*4+c] + (double)Kr[r*4+1]*Er[1*4+c] + (double)Kr[r*4+2]*Er[2*4+c];
                Bm[r][c] = (double)Ks[r*4+0]*Es[0*4+c] + (double)Ks[r*4+1]*Es[1*4+c] + (double)Ks[r*4+2]*Es[2*4+c];
            } else {
                A[r][c]  = (double)Er[12 + c];
                Bm[r][c] = (double)Es[12 + c];
            }
        }
    double M[4][8];
    for (int i = 0; i < 4; i++)
        for (int j = 0; j < 4; j++) { M[i][j] = A[i][j]; M[i][4+j] = (i == j) ? 1.0 : 0.0; }
    for (int col = 0; col < 4; col++) {
        int piv = col;
        for (int r = col + 1; r < 4; r++)
            if (fabs(M[r][col]) > fabs(M[piv][col])) piv = r;
        if (piv != col)
            for (int j = 0; j < 8; j++) { double tmp = M[col][j]; M[col][j] = M[piv][j]; M[piv][j] = tmp; }
        double pv = M[col][col];
        for (int j = 0; j < 8; j++) M[col][j] /= pv;
        for (int r = 0; r < 4; r++) {
            if (r == col) continue;
            double f = M[r][col];
            for (int j = 0; j < 8; j++) M[r][j] -= f * M[col][j];
        }
    }
    float* o = mats + t * 12;
    for (int i = 0; i < 3; i++) {
        double p0 = 0, p1 = 0, p2 = 0, p3 = 0;
        for (int k = 0; k < 4; k++) {
            p0 += Bm[i][k] * M[k][4+0];
            p1 += Bm[i][k] * M[k][4+1];
            p2 += Bm[i][k] * M[k][4+2];
            p3 += Bm[i][k] * M[k][4+3];
        }
        o[i*3+0] = (float)p0; o[i*3+1] = (float)p1; o[i*3+2] = (float)p2;
        o[9 + i] = (float)p3;
    }
}

// ---------------------------------------------------------------------------
// Kernel 1: merged transpose [32][HW] -> [HW][32]; slabs 0-7 = src, 8-9 = ref.
// Block (0,0) additionally computes the 8 projection matrices (tid<8).
// ---------------------------------------------------------------------------
__global__ __launch_bounds__(256) void prep_transpose(const float* __restrict__ src,
                                                      const float* __restrict__ ref,
                                                      const float* __restrict__ proj,
                                                      float* __restrict__ srcT,
                                                      float* __restrict__ refT,
                                                      float* __restrict__ mats) {
    if (blockIdx.x == 0 && blockIdx.y == 0 && threadIdx.x < 8)
        compute_mats(threadIdx.x, proj, mats);

    __shared__ float t[32][33];
    int slab = blockIdx.y;
    const float* ip;
    float* op;
    if (slab < 8) { ip = src + (size_t)slab * 32 * HW; op = srcT + (size_t)slab * 32 * HW; }
    else          { ip = ref + (size_t)(slab - 8) * 32 * HW; op = refT + (size_t)(slab - 8) * 32 * HW; }
    int hw0 = blockIdx.x * 32;
    int tx = threadIdx.x & 31, ty = threadIdx.x >> 5;
#pragma unroll
    for (int i = 0; i < 4; i++) {
        int c = ty + i * 8;
        t[c][tx] = ip[(size_t)c * HW + hw0 + tx];
    }
    __syncthreads();
#pragma unroll
    for (int i = 0; i < 4; i++) {
        int hl = ty + i * 8;
        op[(size_t)(hw0 + hl) * 32 + tx] = t[tx][hl];
    }
}

// ---------------------------------------------------------------------------
// Kernel 2: main fused kernel. Block = 256 threads = one ref pixel.
// Thread (d,g): d = tid>>3 (depth 0..31), g = tid&7 (channel group).
// Phase 0: one homography per lane (n0 = tid&3), shared via octet shuffles.
// Phase 1: gathers + blend-then-dot + octet g-sum -> sL[n][d] (barrier-free).
// Stats  : wave 0 alone computes cw[n][d] + cwsum[d] tables (softmax over D).
// Phase 2: per-thread cf = 4 LDS reads + 4 FMA; logit2 -> sE.
// Final  : wave 0 alone does final softmax, attn writes, argmax depth write.
// ---------------------------------------------------------------------------
__global__ __launch_bounds__(256) void main_kernel(
    const float* __restrict__ srcT,   // (N*B, HW, 32) channels-last
    const float* __restrict__ refT,   // (B,   HW, 32) channels-last
    const float* __restrict__ depth,  // (B, D, H, W) original layout
    const float* __restrict__ mats,   // (B*N, 12) rot row-major + trans
    const float* __restrict__ regw,   // (8,)
    const float* __restrict__ regb,   // (1,)
    float* __restrict__ out)          // [B*HW depth][B*D*HW attn]
{
    int tid = threadIdx.x;
    int g  = tid & 7;
    int d  = tid >> 3;      // 0..31

    int p   = blockIdx.x;   // global pixel 0..B*HW-1
    int b   = p / HW;
    int rem = p - b * HW;
    int y   = rem / WW;
    int x   = rem - y * WW;
    float fx = (float)x, fy = (float)y;

    // this thread's group of the ref feature (one float4)
    float4 R = *(const float4*)(refT + (size_t)p * 32 + g * 4);
    float dep = depth[((size_t)(b * DD + d) * HH + y) * WW + x];
    float rwg = regw[g];
    float rb  = regb[0];

    __shared__ float sL[NN][DD];    // per-source logits over depth
    __shared__ float sCW[NN][DD];   // per-source softmax weights (w/ 1/sqrt(C))
    __shared__ float sCWS[DD];      // sum over sources of cw + 1e-8
    __shared__ float sE[DD];        // final logits over depth
    __shared__ float sDep[DD];      // depth hypothesis per d

    if (g == 0) sDep[d] = dep;

    // ---- Phase 0: one homography per lane, for source n0 = tid&3 at depth d
    float W00, W10, W01, W11;
    int   I00, I10, I01, I11;
    {
        int n0 = tid & 3;
        const float* Mp = mats + (size_t)(b * NN + n0) * 12;
        float ax = Mp[0] * fx + Mp[1] * fy + Mp[2];
        float ay = Mp[3] * fx + Mp[4] * fy + Mp[5];
        float az = Mp[6] * fx + Mp[7] * fy + Mp[8];
        float px = ax * dep + Mp[9];
        float py = ay * dep + Mp[10];
        float pz = az * dep + Mp[11];
        float z  = (pz == 0.f) ? 1e-9f : pz;
        float gx = px / z, gy = py / z;

        float x0f = floorf(gx), y0f = floorf(gy);
        float wx = gx - x0f, wy = gy - y0f;
        bool vx0 = (x0f >= 0.f)  && (x0f <= (float)(WW - 1));
        bool vx1 = (x0f >= -1.f) && (x0f <= (float)(WW - 2));
        bool vy0 = (y0f >= 0.f)  && (y0f <= (float)(HH - 1));
        bool vy1 = (y0f >= -1.f) && (y0f <= (float)(HH - 2));
        W00 = (vx0 && vy0) ? (1.f - wx) * (1.f - wy) : 0.f;
        W10 = (vx1 && vy0) ? wx * (1.f - wy)         : 0.f;
        W01 = (vx0 && vy1) ? (1.f - wx) * wy         : 0.f;
        W11 = (vx1 && vy1) ? wx * wy                 : 0.f;

        int xi0 = (int)fminf(fmaxf(x0f,       0.f), (float)(WW - 1));
        int xi1 = (int)fminf(fmaxf(x0f + 1.f, 0.f), (float)(WW - 1));
        int yi0 = (int)fminf(fmaxf(y0f,       0.f), (float)(HH - 1));
        int yi1 = (int)fminf(fmaxf(y0f + 1.f, 0.f), (float)(HH - 1));
        I00 = yi0 * WW + xi0;
        I10 = yi0 * WW + xi1;
        I01 = yi1 * WW + xi0;
        I11 = yi1 * WW + xi1;
    }

    float cor[NN];

    // ---- Phase 1: gathers + blend-then-dot + octet g-sum; no barriers
#pragma unroll
    for (int n = 0; n < NN; n++) {
        int src_lane = (tid & 56) | n;     // lane holding (n, my d)
        float w00 = __shfl(W00, src_lane);
        float w10 = __shfl(W10, src_lane);
        float w01 = __shfl(W01, src_lane);
        float w11 = __shfl(W11, src_lane);
        int   i00 = __shfl(I00, src_lane);
        int   i10 = __shfl(I10, src_lane);
        int   i01 = __shfl(I01, src_lane);
        int   i11 = __shfl(I11, src_lane);

        const float4* S4 = (const float4*)(srcT + (size_t)(n * BB + b) * (32 * HW));
        float4 a  = S4[(size_t)i00 * 8 + g];
        float4 bq = S4[(size_t)i10 * 8 + g];
        float4 c  = S4[(size_t)i01 * 8 + g];
        float4 e  = S4[(size_t)i11 * 8 + g];

        // blend-then-dot: 4 identical per-component chains (SLP-friendly)
        float wrx = w00 * a.x + w10 * bq.x + w01 * c.x + w11 * e.x;
        float wry = w00 * a.y + w10 * bq.y + w01 * c.y + w11 * e.y;
        float wrz = w00 * a.z + w10 * bq.z + w01 * c.z + w11 * e.z;
        float wrw = w00 * a.w + w10 * bq.w + w01 * c.w + w11 * e.w;
        float cr = wrx * R.x + wry * R.y + wrz * R.z + wrw * R.w;
        cor[n] = cr;

        // sum over the 8 channel-groups (octet butterfly; lane-invariant)
        float ls = cr;
        ls += __shfl_xor(ls, 1);
        ls += __shfl_xor(ls, 2);
        ls += __shfl_xor(ls, 4);
        if (g == 0) sL[n][d] = ls * 0.125f;  // mean over C//G=4 then /attn_temp
    }
    __syncthreads();   // barrier 1: sL fully populated

    // ---- Stats: wave 0 computes cw[n][d] and cwsum[d] for all n,d
    if (tid < 64) {
        int n  = tid >> 4;       // 0..3
        int dh = tid & 15;       // 0..15; covers d=dh and d=dh+16
        float l0 = sL[n][dh];
        float l1 = sL[n][dh + 16];
        float m = fmaxf(l0, l1);
        m = fmaxf(m, __shfl_xor(m, 1));
        m = fmaxf(m, __shfl_xor(m, 2));
        m = fmaxf(m, __shfl_xor(m, 4));
        m = fmaxf(m, __shfl_xor(m, 8));
        float e0 = __expf(l0 - m), e1 = __expf(l1 - m);
        float s = e0 + e1;
        s += __shfl_xor(s, 1);
        s += __shfl_xor(s, 2);
        s += __shfl_xor(s, 4);
        s += __shfl_xor(s, 8);
        float f = 0.17677669529663687f / s;   // fold 1/sqrt(C=32)
        float c0 = e0 * f, c1 = e1 * f;
        sCW[n][dh]      = c0;
        sCW[n][dh + 16] = c1;
        // cross-source sum per depth (lanes with same dh across the 4 n-groups)
        float t0 = c0, t1 = c1;
        t0 += __shfl_xor(t0, 16); t0 += __shfl_xor(t0, 32);
        t1 += __shfl_xor(t1, 16); t1 += __shfl_xor(t1, 32);
        if (n == 0) {
            sCWS[dh]      = t0 + 1e-8f;
            sCWS[dh + 16] = t1 + 1e-8f;
        }
    }
    __syncthreads();   // barrier 2: sCW/sCWS ready

    // ---- Phase 2: per-thread weighted accumulation + reg projection
    float cf = 0.f;
#pragma unroll
    for (int n = 0; n < NN; n++) cf += sCW[n][d] * cor[n];
    cf *= 0.25f;                         // fold mean(C//G=4) factor
    float v = cf * rwg;
    v += __shfl_xor(v, 1);
    v += __shfl_xor(v, 2);
    v += __shfl_xor(v, 4);
    float logit2 = v / sCWS[d] + rb;     // identical across octet
    if (g == 0) sE[d] = logit2;
    __syncthreads();   // barrier 3: sE fully populated

    // ---- Final: wave 0 alone — softmax over D, attn writes, argmax depth
    if (tid < 64) {
        int dl = tid & 31;               // both wave halves compute identically
        float q = sE[dl];
        float m2 = q;
        m2 = fmaxf(m2, __shfl_xor(m2, 1));
        m2 = fmaxf(m2, __shfl_xor(m2, 2));
        m2 = fmaxf(m2, __shfl_xor(m2, 4));
        m2 = fmaxf(m2, __shfl_xor(m2, 8));
        m2 = fmaxf(m2, __shfl_xor(m2, 16));
        float e2 = __expf(q - m2);
        float t2 = e2;
        t2 += __shfl_xor(t2, 1);
        t2 += __shfl_xor(t2, 2);
        t2 += __shfl_xor(t2, 4);
        t2 += __shfl_xor(t2, 8);
        t2 += __shfl_xor(t2, 16);
        float aw = e2 / t2;
        if (tid < 32)
            out[(size_t)BB * HW + (size_t)(b * DD + dl) * HW + rem] = aw;

        // argmax over D (first-max semantics), within each 32-lane half
        float bv = q; int bi = dl;
#pragma unroll
        for (int s = 1; s <= 16; s <<= 1) {
            float ov = __shfl_xor(bv, s);
            int   oi = __shfl_xor(bi, s);
            if (ov > bv || (ov == bv && oi < bi)) { bv = ov; bi = oi; }
        }
        if (tid < 32 && dl == bi) out[p] = sDep[bi];
    }
}

// ---------------------------------------------------------------------------
extern "C" void kernel_launch(void* const* d_in, const int* in_sizes, int n_in,
                              void* d_out, int out_size, void* d_ws, size_t ws_size,
                              hipStream_t stream) {
    const float* ref   = (const float*)d_in[0];  // (B,C,H,W)
    const float* src   = (const float*)d_in[1];  // (N,B,C,H,W)
    const float* proj  = (const float*)d_in[2];  // (B,N+1,2,4,4)
    const float* depth = (const float*)d_in[3];  // (B,D,H,W)
    const float* regw  = (const float*)d_in[4];  // (8,)
    const float* regb  = (const float*)d_in[5];  // (1,)
    float* out = (float*)d_out;

    float* ws   = (float*)d_ws;
    float* mats = ws;                                 // 96 floats (pad to 256)
    float* srcT = ws + 256;                           // N*B*HW*32 = 5,242,880
    float* refT = srcT + (size_t)NN * BB * HW * 32;   // B*HW*32 = 1,310,720

    prep_transpose<<<dim3(HW / 32, 10), 256, 0, stream>>>(src, ref, proj,
                                                          srcT, refT, mats);
    main_kernel<<<BB * HW, 256, 0, stream>>>(srcT, refT, depth, mats,
                                             regw, regb, out);
}